// Round 1
// baseline (209.862 us; speedup 1.0000x reference)
//
#include <hip/hip_runtime.h>

// TrimZeros: reference masks out columns strictly beyond the last nonzero
// column. Those columns are all-zero in the input by definition, so the
// reference output is bitwise-equal (up to ±0.0, which absmax treats as 0)
// to the input for ANY input. The kernel is therefore an identity copy:
// 512 MiB in + 512 MiB out = 1 GiB HBM traffic, memory-bound.
//
// hipMemcpyAsync(D2D, stream) is graph-capture-safe and uses the blit/SDMA
// path (~85% of peak BW), matching or beating a hand-rolled float4 copy.

extern "C" void kernel_launch(void* const* d_in, const int* in_sizes, int n_in,
                              void* d_out, int out_size, void* d_ws, size_t ws_size,
                              hipStream_t stream) {
    const float* x = (const float*)d_in[0];
    float* out = (float*)d_out;
    const size_t bytes = (size_t)out_size * sizeof(float);
    hipMemcpyAsync(out, x, bytes, hipMemcpyDeviceToDevice, stream);
}